// Round 1
// baseline (981.714 us; speedup 1.0000x reference)
//
#include <hip/hip_runtime.h>
#include <math.h>

#define BSZ   16
#define NDIM  128
#define KNEG  65536
#define KP1   65537
#define NDATA 1000000
#define NROWS (BSZ * KP1)        // 1,048,592 (divisible by 8)
#define NPART 1024               // partial-sum slots (power of 2)
#define INV_T (1.0f / 0.07f)

// ---------------------------------------------------------------------------
// Kernel 1: gather rows, dual dot products, exp, raw write + partial sums.
// 32 lanes per row (32 x float4 = 512 B, one coalesced access per row).
// 256 threads/block -> 8 rows/block. Grid = NROWS/8 exactly (no tail).
// ---------------------------------------------------------------------------
__global__ __launch_bounds__(256) void gather_dot_kernel(
    const float* __restrict__ mem, const float* __restrict__ x,
    const float* __restrict__ z, const int* __restrict__ y,
    const int* __restrict__ idx, float* __restrict__ out_lx,
    float* __restrict__ out_lz, double* __restrict__ partials)
{
    __shared__ float s_lx[8];
    const int tid   = threadIdx.x;
    const int group = tid >> 5;        // 0..7
    const int lane  = tid & 31;        // 0..31
    const int r     = blockIdx.x * 8 + group;   // global row id, < NROWS

    const int b = r / KP1;
    const int k = r - b * KP1;
    const int row = (k == 0) ? y[b] : idx[b * KNEG + (k - 1)];

    const float4* mrow = (const float4*)(mem + (size_t)row * NDIM);
    const float4* xr   = (const float4*)(x + b * NDIM);
    const float4* zr   = (const float4*)(z + b * NDIM);

    float4 mv = mrow[lane];
    float4 xv = xr[lane];
    float4 zv = zr[lane];

    float px = mv.x * xv.x + mv.y * xv.y + mv.z * xv.z + mv.w * xv.w;
    float pz = mv.x * zv.x + mv.y * zv.y + mv.z * zv.z + mv.w * zv.w;

    // reduce across the 32-lane group (masks <=16 stay inside the group)
    #pragma unroll
    for (int m = 16; m >= 1; m >>= 1) {
        px += __shfl_xor(px, m, 64);
        pz += __shfl_xor(pz, m, 64);
    }

    if (lane == 0) {
        float lxv = expf(px * INV_T);
        float lzv = expf(pz * INV_T);
        out_lx[r] = lxv;
        out_lz[r] = lzv;
        s_lx[group] = lxv;
    }
    __syncthreads();
    if (tid == 0) {
        double s = 0.0;
        #pragma unroll
        for (int g = 0; g < 8; ++g) s += (double)s_lx[g];
        atomicAdd(&partials[blockIdx.x & (NPART - 1)], s);
    }
}

// ---------------------------------------------------------------------------
// Kernel 2: reduce the 1024 partials -> ws[NPART] = 1/z0 (double).
// ---------------------------------------------------------------------------
__global__ void finalize_kernel(double* __restrict__ ws)
{
    __shared__ double sh[256];
    double s = 0.0;
    for (int i = threadIdx.x; i < NPART; i += 256) s += ws[i];
    sh[threadIdx.x] = s;
    __syncthreads();
    for (int off = 128; off >= 1; off >>= 1) {
        if (threadIdx.x < off) sh[threadIdx.x] += sh[threadIdx.x + off];
        __syncthreads();
    }
    if (threadIdx.x == 0) {
        double z0 = (sh[0] / (double)NROWS) * (double)NDATA;
        ws[NPART] = 1.0 / z0;
    }
}

// ---------------------------------------------------------------------------
// Kernel 3: full memory -> out_mem copy (512 MB), float4 grid-stride.
// ---------------------------------------------------------------------------
__global__ __launch_bounds__(256) void copy_mem_kernel(
    const float4* __restrict__ src, float4* __restrict__ dst)
{
    const int n4 = NDATA * NDIM / 4;   // 32,000,000
    const int stride = gridDim.x * blockDim.x;
    for (int i = blockIdx.x * blockDim.x + threadIdx.x; i < n4; i += stride)
        dst[i] = src[i];
}

// ---------------------------------------------------------------------------
// Kernel 4: scale lx/lz (first 2*NROWS floats of d_out) by 1/z0, in place.
// ---------------------------------------------------------------------------
__global__ __launch_bounds__(256) void scale_kernel(
    float4* __restrict__ lxlz, const double* __restrict__ ws)
{
    const float s = (float)ws[NPART];
    const int n4 = 2 * NROWS / 4;      // 524,296
    const int stride = gridDim.x * blockDim.x;
    for (int i = blockIdx.x * blockDim.x + threadIdx.x; i < n4; i += stride) {
        float4 v = lxlz[i];
        v.x *= s; v.y *= s; v.z *= s; v.w *= s;
        lxlz[i] = v;
    }
}

// ---------------------------------------------------------------------------
// Kernel 5: EMA update of the 16 positive rows, sequential over b
// (np last-wins semantics on duplicate y). One wave, 2 dims/lane.
// ---------------------------------------------------------------------------
__global__ void update_rows_kernel(
    const float* __restrict__ mem, const float* __restrict__ x,
    const int* __restrict__ y, float* __restrict__ out_mem)
{
    const int lane = threadIdx.x;      // 0..63
    for (int b = 0; b < BSZ; ++b) {
        const int row = y[b];
        const size_t mo = (size_t)row * NDIM;
        float2 m  = ((const float2*)(mem + mo))[lane];
        float2 xv = ((const float2*)(x + (size_t)b * NDIM))[lane];
        float w0 = 0.5f * m.x + 0.5f * xv.x;
        float w1 = 0.5f * m.y + 0.5f * xv.y;
        float ss = w0 * w0 + w1 * w1;
        #pragma unroll
        for (int mk = 32; mk >= 1; mk >>= 1) ss += __shfl_xor(ss, mk, 64);
        float inv = 1.0f / sqrtf(ss);
        ((float2*)(out_mem + mo))[lane] = make_float2(w0 * inv, w1 * inv);
    }
}

// ---------------------------------------------------------------------------
extern "C" void kernel_launch(void* const* d_in, const int* in_sizes, int n_in,
                              void* d_out, int out_size, void* d_ws, size_t ws_size,
                              hipStream_t stream)
{
    const float* x   = (const float*)d_in[0];
    const float* z   = (const float*)d_in[1];
    const float* mem = (const float*)d_in[2];
    const int*   y   = (const int*)d_in[3];
    const int*   idx = (const int*)d_in[4];

    float* out_lx  = (float*)d_out;
    float* out_lz  = out_lx + NROWS;
    float* out_mem = out_lz + NROWS;
    double* ws     = (double*)d_ws;    // [0..NPART-1] partials, [NPART] = 1/z0

    // ws is poisoned 0xAA before every launch -> zero the partials.
    hipMemsetAsync(d_ws, 0, NPART * sizeof(double), stream);

    gather_dot_kernel<<<NROWS / 8, 256, 0, stream>>>(
        mem, x, z, y, idx, out_lx, out_lz, ws);
    finalize_kernel<<<1, 256, 0, stream>>>(ws);
    copy_mem_kernel<<<8192, 256, 0, stream>>>(
        (const float4*)mem, (float4*)out_mem);
    scale_kernel<<<2048, 256, 0, stream>>>((float4*)d_out, ws);
    update_rows_kernel<<<1, 64, 0, stream>>>(mem, x, y, out_mem);
}